// Round 6
// baseline (54.177 us; speedup 1.0000x reference)
//
#include <hip/hip_runtime.h>

// mIoU loss: mean over B pairs of (1 - IoU(output[i], target[i])).
// Inputs: d_in[0] = output [B,4] f32, d_in[1] = target [B,4] f32.
// Output: d_out[0] = scalar f32.
//
// Memory-bound streaming reduction: 32 B/pair, 128 MB total @ B=4M.
// R4 established: main loop is path-BW-bound at ~5.9 TB/s effective
// (93% of the 6.3 TB/s D2D ceiling); extra occupancy doesn't help (R3).
// R5: fuse the two-kernel reduction into ONE kernel via last-block-done:
// each block publishes its partial (agent-scope atomic store) and bumps a
// device-scope counter (acq_rel); the last arriver reduces all partials in
// double and writes the mean. Saves the second dispatch + graph gap.
// Counter is zeroed each call by a 4-byte hipMemsetAsync node (poison/replay
// leave it in unknown state otherwise). Partials are read back with
// agent-scope atomic loads so non-coherent per-XCD L2s can't serve stale
// lines (G16). Deterministic: partials are per-block deterministic and the
// final reduce order is fixed regardless of which block performs it.

#define BLOCK 256
#define NBLOCKS 1024   // d_ws: [0,4096) partials, [4096,4100) counter

__global__ __launch_bounds__(BLOCK) void miou_fused(
    const float4* __restrict__ boxA,   // output boxes, one float4 each
    const float4* __restrict__ boxB,   // target boxes
    float* __restrict__ partials,      // [NBLOCKS]
    unsigned* __restrict__ counter,    // zeroed via hipMemsetAsync pre-launch
    float* __restrict__ out,
    int n)                             // number of pairs
{
    int tid = blockIdx.x * BLOCK + threadIdx.x;
    int stride = gridDim.x * BLOCK;

    float acc = 0.0f;
    for (int i = tid; i < n; i += stride) {
        float4 a = boxA[i];  // (x1, y1, x2, y2)
        float4 b = boxB[i];

        float lt_x = fmaxf(a.x, b.x);
        float lt_y = fmaxf(a.y, b.y);
        float rb_x = fminf(a.z, b.z);
        float rb_y = fminf(a.w, b.w);

        float w = fmaxf(rb_x - lt_x, 0.0f);
        float h = fmaxf(rb_y - lt_y, 0.0f);
        float inter = w * h;

        float areaA = (a.z - a.x) * (a.w - a.y);
        float areaB = (b.z - b.x) * (b.w - b.y);
        float uni = areaA + areaB - inter;  // > 0: boxes have wh >= 1

        acc += 1.0f - inter / uni;
    }

    // wave (64-lane) shuffle reduction
    #pragma unroll
    for (int off = 32; off > 0; off >>= 1)
        acc += __shfl_down(acc, off, 64);

    __shared__ float s[BLOCK / 64];
    __shared__ bool isLast;
    int lane = threadIdx.x & 63;
    int wid  = threadIdx.x >> 6;
    if (lane == 0) s[wid] = acc;
    __syncthreads();

    if (threadIdx.x == 0) {
        float t = s[0] + s[1] + s[2] + s[3];
        // publish partial to the coherent point, then signal arrival
        __hip_atomic_store(&partials[blockIdx.x], t,
                           __ATOMIC_RELAXED, __HIP_MEMORY_SCOPE_AGENT);
        unsigned old = __hip_atomic_fetch_add(counter, 1u,
                           __ATOMIC_ACQ_REL, __HIP_MEMORY_SCOPE_AGENT);
        isLast = (old == (unsigned)(NBLOCKS - 1));
    }
    __syncthreads();

    if (isLast) {
        // last block: all partials published. Agent-scope atomic loads read
        // from the coherent point (no stale per-XCD L2 lines). Fixed order
        // -> bitwise-deterministic result.
        double dacc = 0.0;
        #pragma unroll
        for (int j = 0; j < NBLOCKS / BLOCK; ++j) {
            float p = __hip_atomic_load(&partials[threadIdx.x + j * BLOCK],
                          __ATOMIC_RELAXED, __HIP_MEMORY_SCOPE_AGENT);
            dacc += (double)p;
        }

        #pragma unroll
        for (int off = 32; off > 0; off >>= 1)
            dacc += __shfl_down(dacc, off, 64);

        __shared__ double sd[BLOCK / 64];
        if (lane == 0) sd[wid] = dacc;
        __syncthreads();

        if (threadIdx.x == 0) {
            double t = sd[0] + sd[1] + sd[2] + sd[3];
            out[0] = (float)(t / (double)n);  // unconditional d_out overwrite
        }
    }
}

extern "C" void kernel_launch(void* const* d_in, const int* in_sizes, int n_in,
                              void* d_out, int out_size, void* d_ws, size_t ws_size,
                              hipStream_t stream) {
    const float4* boxA = (const float4*)d_in[0];  // output [B,4] f32
    const float4* boxB = (const float4*)d_in[1];  // target [B,4] f32
    int n = in_sizes[0] / 4;                      // number of box pairs

    float*    partials = (float*)d_ws;                          // 4 KB
    unsigned* counter  = (unsigned*)((char*)d_ws + NBLOCKS * 4); // 4 B
    float*    out      = (float*)d_out;

    // counter must be 0 at kernel start every call (poison + replay leave it
    // dirty otherwise). 4-byte memset node is graph-capture legal.
    hipMemsetAsync(counter, 0, sizeof(unsigned), stream);

    miou_fused<<<NBLOCKS, BLOCK, 0, stream>>>(boxA, boxB, partials, counter,
                                              out, n);
}

// Round 7
// 25.551 us; speedup vs baseline: 2.1204x; 2.1204x over previous
//
#include <hip/hip_runtime.h>

// mIoU loss: mean over B pairs of (1 - IoU(output[i], target[i])).
// Inputs: d_in[0] = output [B,4] f32, d_in[1] = target [B,4] f32.
// Output: d_out[0] = scalar f32.
//
// Memory-bound streaming reduction: 32 B/pair, 128 MB total @ B=4M.
// Established across R3-R5:
//  - R3: doubling waves + 4x unroll left kernel time unchanged -> the main
//    loop is path-BW-bound (~5.9 TB/s effective warm, ~93% of the 6.3 TB/s
//    achievable D2D ceiling; half the traffic served by Infinity Cache).
//  - R5: fusing the reduction via device-scope acq_rel atomics cost +29 us
//    (cross-XCD release fencing disrupts the streaming pipe) vs ~3.5 us
//    saved -> the two-dispatch structure is the CHEAPER synchronization.
// This is the R4 kernel (best measured: 25.26 us), reverted verbatim.
// Two-pass deterministic reduction (no float atomics -> bitwise stable
// across graph replays).

#define BLOCK 256
#define NBLOCKS 1024   // partials buffer = 4 KB in d_ws

__global__ __launch_bounds__(BLOCK) void miou_partial(
    const float4* __restrict__ boxA,   // output boxes, one float4 each
    const float4* __restrict__ boxB,   // target boxes
    float* __restrict__ partials,      // [NBLOCKS]
    int n)                             // number of pairs
{
    int tid = blockIdx.x * BLOCK + threadIdx.x;
    int stride = gridDim.x * BLOCK;

    float acc = 0.0f;
    for (int i = tid; i < n; i += stride) {
        float4 a = boxA[i];  // (x1, y1, x2, y2)
        float4 b = boxB[i];

        float lt_x = fmaxf(a.x, b.x);
        float lt_y = fmaxf(a.y, b.y);
        float rb_x = fminf(a.z, b.z);
        float rb_y = fminf(a.w, b.w);

        float w = fmaxf(rb_x - lt_x, 0.0f);
        float h = fmaxf(rb_y - lt_y, 0.0f);
        float inter = w * h;

        float areaA = (a.z - a.x) * (a.w - a.y);
        float areaB = (b.z - b.x) * (b.w - b.y);
        float uni = areaA + areaB - inter;  // > 0: boxes have wh >= 1

        acc += 1.0f - inter / uni;
    }

    // wave (64-lane) shuffle reduction
    #pragma unroll
    for (int off = 32; off > 0; off >>= 1)
        acc += __shfl_down(acc, off, 64);

    __shared__ float s[BLOCK / 64];
    int lane = threadIdx.x & 63;
    int wid  = threadIdx.x >> 6;
    if (lane == 0) s[wid] = acc;
    __syncthreads();

    if (threadIdx.x == 0) {
        float t = 0.0f;
        #pragma unroll
        for (int w2 = 0; w2 < BLOCK / 64; ++w2) t += s[w2];
        partials[blockIdx.x] = t;  // fully rewritten every call
    }
}

// Single-wave final reduce: 1024 partials = 256 float4, 4 per lane.
// No LDS, no __syncthreads - pure shuffle. Sums in double for accuracy.
__global__ __launch_bounds__(64) void miou_final(
    const float4* __restrict__ partials4,  // [NBLOCKS/4]
    float* __restrict__ out, int n)
{
    int lane = threadIdx.x;  // 0..63

    double acc = 0.0;
    #pragma unroll
    for (int j = 0; j < NBLOCKS / 4 / 64; ++j) {   // 4 float4 per lane
        float4 p = partials4[lane + j * 64];
        acc += (double)p.x + (double)p.y + (double)p.z + (double)p.w;
    }

    #pragma unroll
    for (int off = 32; off > 0; off >>= 1)
        acc += __shfl_down(acc, off, 64);

    if (lane == 0)
        out[0] = (float)(acc / (double)n);  // unconditional overwrite of d_out
}

extern "C" void kernel_launch(void* const* d_in, const int* in_sizes, int n_in,
                              void* d_out, int out_size, void* d_ws, size_t ws_size,
                              hipStream_t stream) {
    const float4* boxA = (const float4*)d_in[0];  // output [B,4] f32
    const float4* boxB = (const float4*)d_in[1];  // target [B,4] f32
    int n = in_sizes[0] / 4;                      // number of box pairs

    float* partials = (float*)d_ws;               // NBLOCKS * 4 B = 4 KB scratch
    float* out = (float*)d_out;

    miou_partial<<<NBLOCKS, BLOCK, 0, stream>>>(boxA, boxB, partials, n);
    miou_final<<<1, 64, 0, stream>>>((const float4*)partials, out, n);
}